// Round 8
// baseline (203.014 us; speedup 1.0000x reference)
//
#include <hip/hip_runtime.h>

#define SEQ    2048
#define NHEAD  16
#define HDIM   64
#define DMODEL 1024
#define BATCH  2

typedef __bf16 bf16;
typedef __bf16 bf16x8 __attribute__((ext_vector_type(8)));
typedef __bf16 bf16x4v __attribute__((ext_vector_type(4)));
typedef float  f32x4  __attribute__((ext_vector_type(4)));

typedef const __attribute__((address_space(1))) void* gas_ptr;
typedef __attribute__((address_space(3))) void*       las_ptr;

__device__ __forceinline__ f32x4 mfma16(bf16x8 a, bf16x8 b, f32x4 c) {
  return __builtin_amdgcn_mfma_f32_16x16x32_bf16(a, b, c, 0, 0, 0);
}

__device__ __forceinline__ void gload_lds16(const void* g, void* l) {
  __builtin_amdgcn_global_load_lds((gas_ptr)(unsigned long long)g,
                                   (las_ptr)(unsigned long long)l, 16, 0, 0);
}

// ---------------- fp32 -> bf16 conversion (x | w_qkv | w_proj concatenated) ----
__global__ void convert_all(const float* __restrict__ x, const float* __restrict__ wq,
                            const float* __restrict__ wp, bf16* __restrict__ out) {
  const long long NX = 4194304, NQ = 3145728, NP = 1048576;
  long long i = ((long long)blockIdx.x * blockDim.x + threadIdx.x) * 4;
  if (i >= NX + NQ + NP) return;
  const float* src; long long off;
  if (i < NX)           { src = x;  off = i; }
  else if (i < NX + NQ) { src = wq; off = i - NX; }
  else                  { src = wp; off = i - NX - NQ; }
  float4 f = *reinterpret_cast<const float4*>(src + off);
  bf16x4v r;
  r[0] = (bf16)f.x; r[1] = (bf16)f.y; r[2] = (bf16)f.z; r[3] = (bf16)f.w;
  *reinterpret_cast<bf16x4v*>(out + i) = r;
}

// ---------------- GEMM C = A(M,K) * B(N,K)^T, bf16 in, fp32 acc ---------------
// EPI 0: epilogue scatters Q/K (fragment-ordered, Q pre-scaled) and V^T
//        (fragment-ordered). EPI 1: proj + bias, fp32 out.
template <int EPI>
__global__ __launch_bounds__(256) void gemm_bt(
    const bf16* __restrict__ A, const bf16* __restrict__ B, int K,
    bf16* __restrict__ q, bf16* __restrict__ k, bf16* __restrict__ v,
    const float* __restrict__ bias, float* __restrict__ out) {
  __shared__ alignas(16) bf16 As[2][128 * 32];
  __shared__ alignas(16) bf16 Bs[2][128 * 32];

  const int tid = threadIdx.x;
  const int l = tid & 63, w = tid >> 6;
  const int lr = l & 15, lg = l >> 4;
  const int wr = (w >> 1) * 64, wc = (w & 1) * 64;
  const long long m0 = (long long)blockIdx.x * 128;
  const long long n0 = (long long)blockIdx.y * 128;
  const int crow = tid >> 2, ccol = (tid & 3) * 8;

  auto stage = [&](int kt, int buf) {
    const bf16* a_src = A + (m0 + crow) * K + (long long)kt * 32 + ccol;
    const bf16* b_src = B + (n0 + crow) * K + (long long)kt * 32 + ccol;
    gload_lds16(a_src,           &As[buf][tid * 8]);
    gload_lds16(a_src + 64LL * K, &As[buf][(tid + 256) * 8]);
    gload_lds16(b_src,           &Bs[buf][tid * 8]);
    gload_lds16(b_src + 64LL * K, &Bs[buf][(tid + 256) * 8]);
  };

  f32x4 acc[4][4];
  const f32x4 fz = {0.f, 0.f, 0.f, 0.f};
#pragma unroll
  for (int m = 0; m < 4; ++m)
#pragma unroll
    for (int n = 0; n < 4; ++n) acc[m][n] = fz;

  stage(0, 0);
  const int nk = K >> 5;
  int cur = 0;
  for (int kt = 0; kt < nk; ++kt) {
    __syncthreads();  // drains vmcnt: buf[cur] staged; prev compute done
    if (kt + 1 < nk) stage(kt + 1, cur ^ 1);
    bf16x8 af[4], bfv[4];
#pragma unroll
    for (int m = 0; m < 4; ++m)
      af[m] = *reinterpret_cast<const bf16x8*>(&As[cur][(wr + m * 16 + lr) * 32 + lg * 8]);
#pragma unroll
    for (int n = 0; n < 4; ++n)
      bfv[n] = *reinterpret_cast<const bf16x8*>(&Bs[cur][(wc + n * 16 + lr) * 32 + lg * 8]);
#pragma unroll
    for (int m = 0; m < 4; ++m)
#pragma unroll
      for (int n = 0; n < 4; ++n) acc[m][n] = mfma16(af[m], bfv[n], acc[m][n]);
    cur ^= 1;
  }

#pragma unroll
  for (int m = 0; m < 4; ++m) {
#pragma unroll
    for (int n = 0; n < 4; ++n) {
#pragma unroll
      for (int j = 0; j < 4; ++j) {
        long long grow = m0 + wr + m * 16 + lg * 4 + j;   // row in (B*S)
        long long gcol = n0 + wc + n * 16 + lr;           // col in N
        float val = acc[m][n][j];
        if (EPI == 0) {
          int three = (int)(gcol >> 10);
          int rem = (int)(gcol & 1023);
          int h = rem >> 6, d = rem & 63;
          int b = (int)(grow >> 11), s = (int)(grow & 2047);
          int bh = b * NHEAD + h;
          if (three < 2) {
            // Q/K fragment order: [bh][s/16][d/32][ (s&15)*32 + ((d>>3)&3)*8 + (d&7) ]
            int dst = ((bh * 128 + (s >> 4)) * 2 + (d >> 5)) * 512 +
                      (s & 15) * 32 + ((d >> 3) & 3) * 8 + (d & 7);
            if (three == 0) q[dst] = (bf16)(val * 0.125f);   // pre-scale Q
            else            k[dst] = (bf16)val;
          } else {
            // V^T fragment order: [bh][d/16][s/64][(s>>5)&1][ (d&15)*32 + ((s>>3)&3)*8 + (s&7) ]
            int dst = (((bh * 4 + (d >> 4)) * 32 + (s >> 6)) * 2 + ((s >> 5) & 1)) * 512 +
                      (d & 15) * 32 + ((s >> 3) & 3) * 8 + (s & 7);
            v[dst] = (bf16)val;
          }
        } else {
          out[grow * 1024 + gcol] = val + bias[gcol];
        }
      }
    }
  }
}

// ---------------- causal flash attention, bf16, hd=64 -------------------------
// Round-8: in-block SPLIT-K. 8 waves / 512 threads per block.
//  waves 0-3 ("half A"): q-group's 4 tiles, key-tiles [0, ceil(nk/2))
//  waves 4-7 ("half B"): same tiles,        key-tiles [ceil(nk/2), nk)
// Each half runs independent online softmax; half-B publishes unnormalized
// (o, m, l) to LDS; one barrier; half-A merges (flash combine) and writes ctx.
// Pairing {p, 31-p} kept -> ~17 uniform iterations/wave; 4096 waves total =
// 16 waves/CU (2 blocks x 8 waves). K/V loads stay sunk (r7 lesson: explicit
// reg pipeline hurt). Deferred cross-lane sum reduce (r7 win) kept: 2x/kernel.
__global__ __launch_bounds__(512, 4) void attn_kernel(
    const bf16* __restrict__ qbuf, const bf16* __restrict__ kbuf,
    const bf16* __restrict__ vbuf, bf16* __restrict__ ctx) {
  const int lid = blockIdx.y * gridDim.x + blockIdx.x;  // [0,512)
  const int xcd = lid & 7;
  const int idx = lid >> 3;                             // [0,64)
  const int bh  = xcd + (idx >> 4) * 8;                 // 4 bh per XCD (K+V L2-fit)
  const int p   = idx & 15;                             // pair index [0,16)
  const int tid = threadIdx.x;
  const int l = tid & 63, w = tid >> 6;                 // w in [0,8)
  const int wt = w & 3;                                 // tile-in-group
  const int half = w >> 2;                              // 0 = front keys, 1 = back keys
  const int lr = l & 15, lg = l >> 4;
  const int foff = lr * 32 + lg * 8;

  __shared__ alignas(16) bf16  Pl[8][16][72];   // per-wave P staging (16B-aligned rows)
  __shared__ alignas(16) float Om[4][16][68];   // half-B unnormalized O (padded rows)
  __shared__ float Mm[4][16], Lm[4][16];        // half-B m, l per q-row

  const bf16* Kb = kbuf + bh * 131072 + foff;
  const bf16* Vb = vbuf + bh * 131072 + foff;
  const int b = bh >> 4, h = bh & 15;
  const f32x4 fz = {0.f, 0.f, 0.f, 0.f};

#pragma unroll
  for (int phase = 0; phase < 2; ++phase) {
    const int qg = phase ? (31 - p) : p;       // 64-row q-group
    const int nk = qg + 1;                     // key tiles for this group
    const int hs = (nk + 1) >> 1;              // split point (ceil)
    const int klo = half ? hs : 0;
    const int khi = half ? nk : hs;
    const int qt16 = qg * 4 + wt;              // wave's 16-row q-tile

    const bf16* Qb = qbuf + (bh * 128 + qt16) * 1024 + foff;
    bf16x8 qf[2];
    qf[0] = *reinterpret_cast<const bf16x8*>(Qb);
    qf[1] = *reinterpret_cast<const bf16x8*>(Qb + 512);

    f32x4 o[4];
    float mrow[4], lsum[4];
#pragma unroll
    for (int nd = 0; nd < 4; ++nd) o[nd] = fz;
#pragma unroll
    for (int j = 0; j < 4; ++j) { mrow[j] = -1e30f; lsum[j] = 0.f; }

    for (int kt = klo; kt < khi; ++kt) {
      const bool diag = (kt == qg);

      // V^T fragments first (consumed last -> deepest in flight)
      bf16x8 vf[4][2];
#pragma unroll
      for (int nd = 0; nd < 4; ++nd)
#pragma unroll
        for (int kk = 0; kk < 2; ++kk)
          vf[nd][kk] = *reinterpret_cast<const bf16x8*>(
              &Vb[((nd * 32 + kt) * 2 + kk) * 512]);

      // K fragments
      bf16x8 kf[4][2];
#pragma unroll
      for (int n = 0; n < 4; ++n)
#pragma unroll
        for (int kk = 0; kk < 2; ++kk)
          kf[n][kk] = *reinterpret_cast<const bf16x8*>(
              &Kb[((kt * 4 + n) * 2 + kk) * 512]);

      // QK^T, elementwise causal mask on the diagonal tile
      f32x4 s4[4];
#pragma unroll
      for (int n = 0; n < 4; ++n)
        s4[n] = mfma16(qf[1], kf[n][1], mfma16(qf[0], kf[n][0], fz));
      if (diag) {
#pragma unroll
        for (int n = 0; n < 4; ++n)
#pragma unroll
          for (int j = 0; j < 4; ++j)
            if (n * 16 + lr > wt * 16 + lg * 4 + j) s4[n][j] = -1e30f;
      }

      // online softmax: cross-lane max reduce (16 lanes sharing lg)
      float pm[4];
#pragma unroll
      for (int j = 0; j < 4; ++j)
        pm[j] = fmaxf(fmaxf(s4[0][j], s4[1][j]), fmaxf(s4[2][j], s4[3][j]));
#pragma unroll
      for (int msk = 1; msk <= 8; msk <<= 1)
#pragma unroll
        for (int j = 0; j < 4; ++j) pm[j] = fmaxf(pm[j], __shfl_xor(pm[j], msk, 64));
      float alpha[4];
#pragma unroll
      for (int j = 0; j < 4; ++j) {
        float mn = fmaxf(mrow[j], pm[j]);
        alpha[j] = __expf(mrow[j] - mn);
        mrow[j] = mn;
      }
      float rs[4] = {0.f, 0.f, 0.f, 0.f};
#pragma unroll
      for (int n = 0; n < 4; ++n)
#pragma unroll
        for (int j = 0; j < 4; ++j) {
          float pv = __expf(s4[n][j] - mrow[j]);
          s4[n][j] = pv;
          rs[j] += pv;            // per-lane partial (deferred cross-lane reduce)
        }
#pragma unroll
      for (int j = 0; j < 4; ++j) lsum[j] = lsum[j] * alpha[j] + rs[j];
#pragma unroll
      for (int nd = 0; nd < 4; ++nd)
#pragma unroll
        for (int j = 0; j < 4; ++j) o[nd][j] *= alpha[j];

      // P -> per-wave LDS (C-layout -> A-fragment layout)
#pragma unroll
      for (int n = 0; n < 4; ++n)
#pragma unroll
        for (int j = 0; j < 4; ++j)
          Pl[w][lg * 4 + j][n * 16 + lr] = (bf16)s4[n][j];

      // PV
#pragma unroll
      for (int kk = 0; kk < 2; ++kk) {
        bf16x8 pf = *reinterpret_cast<const bf16x8*>(&Pl[w][lr][kk * 32 + lg * 8]);
#pragma unroll
        for (int nd = 0; nd < 4; ++nd)
          o[nd] = mfma16(pf, vf[nd][kk], o[nd]);
      }
    }

    // finalize this half: cross-lane sum reduce (once per phase)
    float ls[4];
#pragma unroll
    for (int j = 0; j < 4; ++j) ls[j] = lsum[j];
#pragma unroll
    for (int msk = 1; msk <= 8; msk <<= 1)
#pragma unroll
      for (int j = 0; j < 4; ++j) ls[j] += __shfl_xor(ls[j], msk, 64);

    if (half) {
      // publish unnormalized (o, m, l)
#pragma unroll
      for (int nd = 0; nd < 4; ++nd)
#pragma unroll
        for (int j = 0; j < 4; ++j)
          Om[wt][lg * 4 + j][nd * 16 + lr] = o[nd][j];
      if (lr == 0) {
#pragma unroll
        for (int j = 0; j < 4; ++j) {
          Mm[wt][lg * 4 + j] = mrow[j];
          Lm[wt][lg * 4 + j] = ls[j];
        }
      }
    }
    __syncthreads();   // half-B state visible
    if (!half) {
      float wA[4], wB[4], inv[4];
#pragma unroll
      for (int j = 0; j < 4; ++j) {
        float mB = Mm[wt][lg * 4 + j];
        float lB = Lm[wt][lg * 4 + j];
        float mM = fmaxf(mrow[j], mB);
        wA[j] = __expf(mrow[j] - mM);
        wB[j] = __expf(mB - mM);
        inv[j] = 1.0f / (ls[j] * wA[j] + lB * wB[j]);
      }
      const int qr0 = qt16 * 16;
#pragma unroll
      for (int nd = 0; nd < 4; ++nd)
#pragma unroll
        for (int j = 0; j < 4; ++j) {
          float oB = Om[wt][lg * 4 + j][nd * 16 + lr];
          int srow = qr0 + lg * 4 + j;
          int d = nd * 16 + lr;
          ctx[((long long)(b * SEQ + srow)) * DMODEL + h * HDIM + d] =
              (bf16)((o[nd][j] * wA[j] + oB * wB[j]) * inv[j]);
        }
    }
    __syncthreads();   // protect Om/Mm/Lm reuse in next phase
  }
}

extern "C" void kernel_launch(void* const* d_in, const int* in_sizes, int n_in,
                              void* d_out, int out_size, void* d_ws, size_t ws_size,
                              hipStream_t stream) {
  const float* x      = (const float*)d_in[0];
  const float* w_qkv  = (const float*)d_in[1];
  const float* w_proj = (const float*)d_in[2];
  const float* b_proj = (const float*)d_in[3];
  float* out = (float*)d_out;

  bf16* ws = (bf16*)d_ws;
  bf16* xb     = ws;                   // 4194304 elems
  bf16* wqkvb  = xb + 4194304;         // 3145728
  bf16* wprojb = wqkvb + 3145728;      // 1048576
  bf16* qb     = wprojb + 1048576;     // 4194304 (fragment-ordered, pre-scaled)
  bf16* kb     = qb + 4194304;         // 4194304 (fragment-ordered)
  bf16* vb     = kb + 4194304;         // 4194304 (V^T fragment-ordered)
  bf16* ctxb   = vb + 4194304;         // 4194304   total ~48 MB

  convert_all<<<8192, 256, 0, stream>>>(x, w_qkv, w_proj, xb);
  gemm_bt<0><<<dim3(32, 24), 256, 0, stream>>>(xb, wqkvb, 1024, qb, kb, vb, nullptr, nullptr);
  attn_kernel<<<dim3(16, 32), 512, 0, stream>>>(qb, kb, vb, ctxb);
  gemm_bt<1><<<dim3(32, 8), 256, 0, stream>>>(ctxb, wprojb, 1024, nullptr, nullptr, nullptr,
                                              b_proj, out);
}

// Round 10
// 202.236 us; speedup vs baseline: 1.0039x; 1.0039x over previous
//
#include <hip/hip_runtime.h>

#define SEQ    2048
#define NHEAD  16
#define HDIM   64
#define DMODEL 1024
#define BATCH  2

typedef __bf16 bf16;
typedef __bf16 bf16x8 __attribute__((ext_vector_type(8)));
typedef __bf16 bf16x4v __attribute__((ext_vector_type(4)));
typedef float  f32x4  __attribute__((ext_vector_type(4)));

typedef const __attribute__((address_space(1))) void* gas_ptr;
typedef __attribute__((address_space(3))) void*       las_ptr;

__device__ __forceinline__ f32x4 mfma16(bf16x8 a, bf16x8 b, f32x4 c) {
  return __builtin_amdgcn_mfma_f32_16x16x32_bf16(a, b, c, 0, 0, 0);
}

__device__ __forceinline__ void gload_lds16(const void* g, void* l) {
  __builtin_amdgcn_global_load_lds((gas_ptr)(unsigned long long)g,
                                   (las_ptr)(unsigned long long)l, 16, 0, 0);
}

// ---------------- fp32 -> bf16 conversion (x | w_qkv | w_proj concatenated) ----
__global__ void convert_all(const float* __restrict__ x, const float* __restrict__ wq,
                            const float* __restrict__ wp, bf16* __restrict__ out) {
  const long long NX = 4194304, NQ = 3145728, NP = 1048576;
  long long i = ((long long)blockIdx.x * blockDim.x + threadIdx.x) * 4;
  if (i >= NX + NQ + NP) return;
  const float* src; long long off;
  if (i < NX)           { src = x;  off = i; }
  else if (i < NX + NQ) { src = wq; off = i - NX; }
  else                  { src = wp; off = i - NX - NQ; }
  float4 f = *reinterpret_cast<const float4*>(src + off);
  bf16x4v r;
  r[0] = (bf16)f.x; r[1] = (bf16)f.y; r[2] = (bf16)f.z; r[3] = (bf16)f.w;
  *reinterpret_cast<bf16x4v*>(out + i) = r;
}

// ---------------- GEMM C = A(M,K) * B(N,K)^T, bf16 in, fp32 acc ---------------
// EPI 0: epilogue scatters Q/K (fragment-ordered; Q pre-scaled by
//        SCALE*log2(e) so attention softmax can use exp2 directly) and V^T
//        (fragment-ordered). EPI 1: proj + bias, fp32 out.
template <int EPI>
__global__ __launch_bounds__(256) void gemm_bt(
    const bf16* __restrict__ A, const bf16* __restrict__ B, int K,
    bf16* __restrict__ q, bf16* __restrict__ k, bf16* __restrict__ v,
    const float* __restrict__ bias, float* __restrict__ out) {
  __shared__ alignas(16) bf16 As[2][128 * 32];
  __shared__ alignas(16) bf16 Bs[2][128 * 32];

  const int tid = threadIdx.x;
  const int l = tid & 63, w = tid >> 6;
  const int lr = l & 15, lg = l >> 4;
  const int wr = (w >> 1) * 64, wc = (w & 1) * 64;
  const long long m0 = (long long)blockIdx.x * 128;
  const long long n0 = (long long)blockIdx.y * 128;
  const int crow = tid >> 2, ccol = (tid & 3) * 8;

  auto stage = [&](int kt, int buf) {
    const bf16* a_src = A + (m0 + crow) * K + (long long)kt * 32 + ccol;
    const bf16* b_src = B + (n0 + crow) * K + (long long)kt * 32 + ccol;
    gload_lds16(a_src,           &As[buf][tid * 8]);
    gload_lds16(a_src + 64LL * K, &As[buf][(tid + 256) * 8]);
    gload_lds16(b_src,           &Bs[buf][tid * 8]);
    gload_lds16(b_src + 64LL * K, &Bs[buf][(tid + 256) * 8]);
  };

  f32x4 acc[4][4];
  const f32x4 fz = {0.f, 0.f, 0.f, 0.f};
#pragma unroll
  for (int m = 0; m < 4; ++m)
#pragma unroll
    for (int n = 0; n < 4; ++n) acc[m][n] = fz;

  stage(0, 0);
  const int nk = K >> 5;
  int cur = 0;
  for (int kt = 0; kt < nk; ++kt) {
    __syncthreads();  // drains vmcnt: buf[cur] staged; prev compute done
    if (kt + 1 < nk) stage(kt + 1, cur ^ 1);
    bf16x8 af[4], bfv[4];
#pragma unroll
    for (int m = 0; m < 4; ++m)
      af[m] = *reinterpret_cast<const bf16x8*>(&As[cur][(wr + m * 16 + lr) * 32 + lg * 8]);
#pragma unroll
    for (int n = 0; n < 4; ++n)
      bfv[n] = *reinterpret_cast<const bf16x8*>(&Bs[cur][(wc + n * 16 + lr) * 32 + lg * 8]);
#pragma unroll
    for (int m = 0; m < 4; ++m)
#pragma unroll
      for (int n = 0; n < 4; ++n) acc[m][n] = mfma16(af[m], bfv[n], acc[m][n]);
    cur ^= 1;
  }

#pragma unroll
  for (int m = 0; m < 4; ++m) {
#pragma unroll
    for (int n = 0; n < 4; ++n) {
#pragma unroll
      for (int j = 0; j < 4; ++j) {
        long long grow = m0 + wr + m * 16 + lg * 4 + j;   // row in (B*S)
        long long gcol = n0 + wc + n * 16 + lr;           // col in N
        float val = acc[m][n][j];
        if (EPI == 0) {
          int three = (int)(gcol >> 10);
          int rem = (int)(gcol & 1023);
          int h = rem >> 6, d = rem & 63;
          int b = (int)(grow >> 11), s = (int)(grow & 2047);
          int bh = b * NHEAD + h;
          if (three < 2) {
            // Q/K fragment order: [bh][s/16][d/32][ (s&15)*32 + ((d>>3)&3)*8 + (d&7) ]
            int dst = ((bh * 128 + (s >> 4)) * 2 + (d >> 5)) * 512 +
                      (s & 15) * 32 + ((d >> 3) & 3) * 8 + (d & 7);
            // Q pre-scaled by SCALE*log2(e) = 0.125 * 1.4426950 (exp2 softmax)
            if (three == 0) q[dst] = (bf16)(val * 0.18033688f);
            else            k[dst] = (bf16)val;
          } else {
            // V^T fragment order: [bh][d/16][s/64][(s>>5)&1][ (d&15)*32 + ((s>>3)&3)*8 + (s&7) ]
            int dst = (((bh * 4 + (d >> 4)) * 32 + (s >> 6)) * 2 + ((s >> 5) & 1)) * 512 +
                      (d & 15) * 32 + ((s >> 3) & 3) * 8 + (s & 7);
            v[dst] = (bf16)val;
          }
        } else {
          out[grow * 1024 + gcol] = val + bias[gcol];
        }
      }
    }
  }
}

// ---------------- causal flash attention, bf16, hd=64 -------------------------
// Round-9 (attn only, on the r8 split-K structure):
//  (1) T13 deferred-max: per-lane dmax test (no cross-lane); full 4-round
//      shuffle max-reduce + alpha rescale ONLY when __any(dmax > 11) —
//      rare after each q-tile's first key-tile. P bounded by 2^11 (bf16-safe).
//  (2) exp2-direct softmax: Q pre-scaled by SCALE*log2e, exp2f everywhere
//      (bare v_exp_f32, no per-element multiply); merge in log2 domain.
__global__ __launch_bounds__(512, 4) void attn_kernel(
    const bf16* __restrict__ qbuf, const bf16* __restrict__ kbuf,
    const bf16* __restrict__ vbuf, bf16* __restrict__ ctx) {
  const int lid = blockIdx.y * gridDim.x + blockIdx.x;  // [0,512)
  const int xcd = lid & 7;
  const int idx = lid >> 3;                             // [0,64)
  const int bh  = xcd + (idx >> 4) * 8;                 // 4 bh per XCD (K+V L2-fit)
  const int p   = idx & 15;                             // pair index [0,16)
  const int tid = threadIdx.x;
  const int l = tid & 63, w = tid >> 6;                 // w in [0,8)
  const int wt = w & 3;                                 // tile-in-group
  const int half = w >> 2;                              // 0 = front keys, 1 = back keys
  const int lr = l & 15, lg = l >> 4;
  const int foff = lr * 32 + lg * 8;

  __shared__ alignas(16) bf16  Pl[8][16][72];   // per-wave P staging (16B-aligned rows)
  __shared__ alignas(16) float Om[4][16][68];   // half-B unnormalized O (padded rows)
  __shared__ float Mm[4][16], Lm[4][16];        // half-B m, l per q-row

  const bf16* Kb = kbuf + bh * 131072 + foff;
  const bf16* Vb = vbuf + bh * 131072 + foff;
  const int b = bh >> 4, h = bh & 15;
  const f32x4 fz = {0.f, 0.f, 0.f, 0.f};

#pragma unroll
  for (int phase = 0; phase < 2; ++phase) {
    const int qg = phase ? (31 - p) : p;       // 64-row q-group
    const int nk = qg + 1;                     // key tiles for this group
    const int hs = (nk + 1) >> 1;              // split point (ceil)
    const int klo = half ? hs : 0;
    const int khi = half ? nk : hs;
    const int qt16 = qg * 4 + wt;              // wave's 16-row q-tile

    const bf16* Qb = qbuf + (bh * 128 + qt16) * 1024 + foff;
    bf16x8 qf[2];
    qf[0] = *reinterpret_cast<const bf16x8*>(Qb);
    qf[1] = *reinterpret_cast<const bf16x8*>(Qb + 512);

    f32x4 o[4];
    float mrow[4], lsum[4];
#pragma unroll
    for (int nd = 0; nd < 4; ++nd) o[nd] = fz;
#pragma unroll
    for (int j = 0; j < 4; ++j) { mrow[j] = -1e30f; lsum[j] = 0.f; }

    for (int kt = klo; kt < khi; ++kt) {
      const bool diag = (kt == qg);

      // V^T fragments first (consumed last -> deepest in flight)
      bf16x8 vf[4][2];
#pragma unroll
      for (int nd = 0; nd < 4; ++nd)
#pragma unroll
        for (int kk = 0; kk < 2; ++kk)
          vf[nd][kk] = *reinterpret_cast<const bf16x8*>(
              &Vb[((nd * 32 + kt) * 2 + kk) * 512]);

      // K fragments
      bf16x8 kf[4][2];
#pragma unroll
      for (int n = 0; n < 4; ++n)
#pragma unroll
        for (int kk = 0; kk < 2; ++kk)
          kf[n][kk] = *reinterpret_cast<const bf16x8*>(
              &Kb[((kt * 4 + n) * 2 + kk) * 512]);

      // QK^T (log2-domain scores), elementwise causal mask on diagonal tile
      f32x4 s4[4];
#pragma unroll
      for (int n = 0; n < 4; ++n)
        s4[n] = mfma16(qf[1], kf[n][1], mfma16(qf[0], kf[n][0], fz));
      if (diag) {
#pragma unroll
        for (int n = 0; n < 4; ++n)
#pragma unroll
          for (int j = 0; j < 4; ++j)
            if (n * 16 + lr > wt * 16 + lg * 4 + j) s4[n][j] = -1e30f;
      }

      // T13 deferred-max: cheap per-lane test, full reduce+rescale only if needed
      float pm[4];
      float dmax = -1e30f;
#pragma unroll
      for (int j = 0; j < 4; ++j) {
        pm[j] = fmaxf(fmaxf(s4[0][j], s4[1][j]), fmaxf(s4[2][j], s4[3][j]));
        dmax = fmaxf(dmax, pm[j] - mrow[j]);
      }
      if (__any(dmax > 11.0f)) {
#pragma unroll
        for (int msk = 1; msk <= 8; msk <<= 1)
#pragma unroll
          for (int j = 0; j < 4; ++j) pm[j] = fmaxf(pm[j], __shfl_xor(pm[j], msk, 64));
#pragma unroll
        for (int j = 0; j < 4; ++j) {
          float mn = fmaxf(mrow[j], pm[j]);
          float alpha = exp2f(mrow[j] - mn);
          mrow[j] = mn;
          lsum[j] *= alpha;
#pragma unroll
          for (int nd = 0; nd < 4; ++nd) o[nd][j] *= alpha;
        }
      }

      // P = exp2(s - m), per-lane partial row-sums (deferred cross-lane reduce)
      float rs[4] = {0.f, 0.f, 0.f, 0.f};
#pragma unroll
      for (int n = 0; n < 4; ++n)
#pragma unroll
        for (int j = 0; j < 4; ++j) {
          float pv = exp2f(s4[n][j] - mrow[j]);
          s4[n][j] = pv;
          rs[j] += pv;
        }
#pragma unroll
      for (int j = 0; j < 4; ++j) lsum[j] += rs[j];

      // P -> per-wave LDS (C-layout -> A-fragment layout)
#pragma unroll
      for (int n = 0; n < 4; ++n)
#pragma unroll
        for (int j = 0; j < 4; ++j)
          Pl[w][lg * 4 + j][n * 16 + lr] = (bf16)s4[n][j];

      // PV
#pragma unroll
      for (int kk = 0; kk < 2; ++kk) {
        bf16x8 pf = *reinterpret_cast<const bf16x8*>(&Pl[w][lr][kk * 32 + lg * 8]);
#pragma unroll
        for (int nd = 0; nd < 4; ++nd)
          o[nd] = mfma16(pf, vf[nd][kk], o[nd]);
      }
    }

    // finalize this half: cross-lane sum reduce (once per phase)
    float ls[4];
#pragma unroll
    for (int j = 0; j < 4; ++j) ls[j] = lsum[j];
#pragma unroll
    for (int msk = 1; msk <= 8; msk <<= 1)
#pragma unroll
      for (int j = 0; j < 4; ++j) ls[j] += __shfl_xor(ls[j], msk, 64);

    if (half) {
      // publish unnormalized (o, m, l)
#pragma unroll
      for (int nd = 0; nd < 4; ++nd)
#pragma unroll
        for (int j = 0; j < 4; ++j)
          Om[wt][lg * 4 + j][nd * 16 + lr] = o[nd][j];
      if (lr == 0) {
#pragma unroll
        for (int j = 0; j < 4; ++j) {
          Mm[wt][lg * 4 + j] = mrow[j];
          Lm[wt][lg * 4 + j] = ls[j];
        }
      }
    }
    __syncthreads();   // half-B state visible
    if (!half) {
      float wA[4], wB[4], inv[4];
#pragma unroll
      for (int j = 0; j < 4; ++j) {
        float mB = Mm[wt][lg * 4 + j];
        float lB = Lm[wt][lg * 4 + j];
        float mM = fmaxf(mrow[j], mB);
        wA[j] = exp2f(mrow[j] - mM);
        wB[j] = exp2f(mB - mM);
        inv[j] = 1.0f / (ls[j] * wA[j] + lB * wB[j]);
      }
      const int qr0 = qt16 * 16;
#pragma unroll
      for (int nd = 0; nd < 4; ++nd)
#pragma unroll
        for (int j = 0; j < 4; ++j) {
          float oB = Om[wt][lg * 4 + j][nd * 16 + lr];
          int srow = qr0 + lg * 4 + j;
          int d = nd * 16 + lr;
          ctx[((long long)(b * SEQ + srow)) * DMODEL + h * HDIM + d] =
              (bf16)((o[nd][j] * wA[j] + oB * wB[j]) * inv[j]);
        }
    }
    __syncthreads();   // protect Om/Mm/Lm reuse in next phase
  }
}

extern "C" void kernel_launch(void* const* d_in, const int* in_sizes, int n_in,
                              void* d_out, int out_size, void* d_ws, size_t ws_size,
                              hipStream_t stream) {
  const float* x      = (const float*)d_in[0];
  const float* w_qkv  = (const float*)d_in[1];
  const float* w_proj = (const float*)d_in[2];
  const float* b_proj = (const float*)d_in[3];
  float* out = (float*)d_out;

  bf16* ws = (bf16*)d_ws;
  bf16* xb     = ws;                   // 4194304 elems
  bf16* wqkvb  = xb + 4194304;         // 3145728
  bf16* wprojb = wqkvb + 3145728;      // 1048576
  bf16* qb     = wprojb + 1048576;     // 4194304 (fragment-ordered, pre-scaled)
  bf16* kb     = qb + 4194304;         // 4194304 (fragment-ordered)
  bf16* vb     = kb + 4194304;         // 4194304 (V^T fragment-ordered)
  bf16* ctxb   = vb + 4194304;         // 4194304   total ~48 MB

  convert_all<<<8192, 256, 0, stream>>>(x, w_qkv, w_proj, xb);
  gemm_bt<0><<<dim3(32, 24), 256, 0, stream>>>(xb, wqkvb, 1024, qb, kb, vb, nullptr, nullptr);
  attn_kernel<<<dim3(16, 32), 512, 0, stream>>>(qb, kb, vb, ctxb);
  gemm_bt<1><<<dim3(32, 8), 256, 0, stream>>>(ctxb, wprojb, 1024, nullptr, nullptr, nullptr,
                                              b_proj, out);
}

// Round 13
// 186.800 us; speedup vs baseline: 1.0868x; 1.0826x over previous
//
#include <hip/hip_runtime.h>

#define SEQ    2048
#define NHEAD  16
#define HDIM   64
#define DMODEL 1024
#define BATCH  2

typedef __bf16 bf16;
typedef __bf16 bf16x8 __attribute__((ext_vector_type(8)));
typedef __bf16 bf16x4v __attribute__((ext_vector_type(4)));
typedef float  f32x4  __attribute__((ext_vector_type(4)));

typedef const __attribute__((address_space(1))) void* gas_ptr;
typedef __attribute__((address_space(3))) void*       las_ptr;

__device__ __forceinline__ f32x4 mfma16(bf16x8 a, bf16x8 b, f32x4 c) {
  return __builtin_amdgcn_mfma_f32_16x16x32_bf16(a, b, c, 0, 0, 0);
}

__device__ __forceinline__ void gload_lds16(const void* g, void* l) {
  __builtin_amdgcn_global_load_lds((gas_ptr)(unsigned long long)g,
                                   (las_ptr)(unsigned long long)l, 16, 0, 0);
}

// ---------------- fp32 -> bf16 conversion (x | w_qkv | w_proj concatenated) ----
__global__ void convert_all(const float* __restrict__ x, const float* __restrict__ wq,
                            const float* __restrict__ wp, bf16* __restrict__ out) {
  const long long NX = 4194304, NQ = 3145728, NP = 1048576;
  long long i = ((long long)blockIdx.x * blockDim.x + threadIdx.x) * 4;
  if (i >= NX + NQ + NP) return;
  const float* src; long long off;
  if (i < NX)           { src = x;  off = i; }
  else if (i < NX + NQ) { src = wq; off = i - NX; }
  else                  { src = wp; off = i - NX - NQ; }
  float4 f = *reinterpret_cast<const float4*>(src + off);
  bf16x4v r;
  r[0] = (bf16)f.x; r[1] = (bf16)f.y; r[2] = (bf16)f.z; r[3] = (bf16)f.w;
  *reinterpret_cast<bf16x4v*>(out + i) = r;
}

// ---------------- GEMM C = A(M,K) * B(N,K)^T, bf16 in, fp32 acc ---------------
// EPI 0: epilogue scatters Q/K and V^T in LANE-SLOT fragment order: within
//        each 1KB fragment, lane l's MFMA operand slice lives at byte l*16,
//        so LDS staging (linear DMA) and ds_read_b128 are both the canonical
//        lane-contiguous conflict-free pattern. Q pre-scaled by SCALE*log2e.
// EPI 1: proj + bias, fp32 out.
template <int EPI>
__global__ __launch_bounds__(256) void gemm_bt(
    const bf16* __restrict__ A, const bf16* __restrict__ B, int K,
    bf16* __restrict__ q, bf16* __restrict__ k, bf16* __restrict__ v,
    const float* __restrict__ bias, float* __restrict__ out) {
  __shared__ alignas(16) bf16 As[2][128 * 32];
  __shared__ alignas(16) bf16 Bs[2][128 * 32];

  const int tid = threadIdx.x;
  const int l = tid & 63, w = tid >> 6;
  const int lr = l & 15, lg = l >> 4;
  const int wr = (w >> 1) * 64, wc = (w & 1) * 64;
  const long long m0 = (long long)blockIdx.x * 128;
  const long long n0 = (long long)blockIdx.y * 128;
  const int crow = tid >> 2, ccol = (tid & 3) * 8;

  auto stage = [&](int kt, int buf) {
    const bf16* a_src = A + (m0 + crow) * K + (long long)kt * 32 + ccol;
    const bf16* b_src = B + (n0 + crow) * K + (long long)kt * 32 + ccol;
    gload_lds16(a_src,           &As[buf][tid * 8]);
    gload_lds16(a_src + 64LL * K, &As[buf][(tid + 256) * 8]);
    gload_lds16(b_src,           &Bs[buf][tid * 8]);
    gload_lds16(b_src + 64LL * K, &Bs[buf][(tid + 256) * 8]);
  };

  f32x4 acc[4][4];
  const f32x4 fz = {0.f, 0.f, 0.f, 0.f};
#pragma unroll
  for (int m = 0; m < 4; ++m)
#pragma unroll
    for (int n = 0; n < 4; ++n) acc[m][n] = fz;

  stage(0, 0);
  const int nk = K >> 5;
  int cur = 0;
  for (int kt = 0; kt < nk; ++kt) {
    __syncthreads();  // drains vmcnt: buf[cur] staged; prev compute done
    if (kt + 1 < nk) stage(kt + 1, cur ^ 1);
    bf16x8 af[4], bfv[4];
#pragma unroll
    for (int m = 0; m < 4; ++m)
      af[m] = *reinterpret_cast<const bf16x8*>(&As[cur][(wr + m * 16 + lr) * 32 + lg * 8]);
#pragma unroll
    for (int n = 0; n < 4; ++n)
      bfv[n] = *reinterpret_cast<const bf16x8*>(&Bs[cur][(wc + n * 16 + lr) * 32 + lg * 8]);
#pragma unroll
    for (int m = 0; m < 4; ++m)
#pragma unroll
      for (int n = 0; n < 4; ++n) acc[m][n] = mfma16(af[m], bfv[n], acc[m][n]);
    cur ^= 1;
  }

#pragma unroll
  for (int m = 0; m < 4; ++m) {
#pragma unroll
    for (int n = 0; n < 4; ++n) {
#pragma unroll
      for (int j = 0; j < 4; ++j) {
        long long grow = m0 + wr + m * 16 + lg * 4 + j;   // row in (B*S)
        long long gcol = n0 + wc + n * 16 + lr;           // col in N
        float val = acc[m][n][j];
        if (EPI == 0) {
          int three = (int)(gcol >> 10);
          int rem = (int)(gcol & 1023);
          int h = rem >> 6, d = rem & 63;
          int b = (int)(grow >> 11), s = (int)(grow & 2047);
          int bh = b * NHEAD + h;
          if (three < 2) {
            // Q/K frag [bh][s/16][d/32]; within: (s&15)*8 + ((d>>3)&3)*128 + (d&7)
            int dst = ((bh * 128 + (s >> 4)) * 2 + (d >> 5)) * 512 +
                      (s & 15) * 8 + ((d >> 3) & 3) * 128 + (d & 7);
            // Q pre-scaled by SCALE*log2(e) = 0.125 * 1.4426950 (exp2 softmax)
            if (three == 0) q[dst] = (bf16)(val * 0.18033688f);
            else            k[dst] = (bf16)val;
          } else {
            // V^T frag [bh][d/16][s/64][(s>>5)&1]; within: (d&15)*8 + ((s>>3)&3)*128 + (s&7)
            int dst = (((bh * 4 + (d >> 4)) * 32 + (s >> 6)) * 2 + ((s >> 5) & 1)) * 512 +
                      (d & 15) * 8 + ((s >> 3) & 3) * 128 + (s & 7);
            v[dst] = (bf16)val;
          }
        } else {
          out[grow * 1024 + gcol] = val + bias[gcol];
        }
      }
    }
  }
}

// ---------------- causal flash attention, bf16, hd=64 -------------------------
// Round-13 = round-12 resubmitted (broker timeout, never measured):
// r11 LDS-staging structure with the K-stride fix (4096 elements, not 8192).
//  - 4 waves / 256 thr, wave owns one 16-row q-tile, pairing {p,31-p}
//    flattened to 33 uniform iterations.
//  - Per key-tile: block stages K(8KB)+V(8KB) ONCE via global_load_lds,
//    double-buffered, prefetch issued one iteration ahead; one __syncthreads
//    per iteration (its vmcnt(0) drain IS the pipeline wait).
//  - Fragments in lane-slot order: ds_read_b128 at byte l*16 (conflict-free).
//  - Softmax: T13 deferred-max + exp2-direct + deferred cross-lane sum.
__global__ __launch_bounds__(256, 2) void attn_kernel(
    const bf16* __restrict__ qbuf, const bf16* __restrict__ kbuf,
    const bf16* __restrict__ vbuf, bf16* __restrict__ ctx) {
  const int lid = blockIdx.y * gridDim.x + blockIdx.x;  // [0,512)
  const int xcd = lid & 7;
  const int idx = lid >> 3;                             // [0,64)
  const int bh  = xcd + (idx >> 4) * 8;                 // 4 bh per XCD (K+V L2-fit)
  const int p   = idx & 15;                             // pair index [0,16)
  const int tid = threadIdx.x;
  const int l = tid & 63, w = tid >> 6;                 // 4 waves
  const int lr = l & 15, lg = l >> 4;
  const int loff = l * 8;                               // lane slot (elements)

  __shared__ alignas(16) bf16 Ks[2][4096];              // K tile: 8 frags x 1KB
  __shared__ alignas(16) bf16 Vs[2][4096];              // V tile: 8 frags x 1KB
  __shared__ alignas(16) bf16 Pl[4][16][72];            // per-wave P staging

  const bf16* Kg = kbuf + bh * 131072;
  const bf16* Vg = vbuf + bh * 131072;
  const int b = bh >> 4, h = bh & 15;
  const f32x4 fz = {0.f, 0.f, 0.f, 0.f};

  // wave w stages K chunks {2w,2w+1} and V chunks {2w,2w+1} (1KB each)
  auto stage = [&](int kt, int sb) {
#pragma unroll
    for (int j = 0; j < 2; ++j) {
      const int c = 2 * w + j;
      gload_lds16(Kg + kt * 4096 + c * 512 + loff, &Ks[sb][c * 512 + loff]);
      gload_lds16(Vg + w * 32768 + kt * 1024 + j * 512 + loff, &Vs[sb][c * 512 + loff]);
    }
  };

  f32x4 o[4];
  float mrow[4], lsum[4];
  bf16x8 qf[2];

  stage(0, 0);
  __syncthreads();   // prologue drain: buf 0 staged
  int buf = 0;

  for (int i = 0; i < 33; ++i) {
    const bool in_a = (i <= p);
    const int qt = in_a ? p : 31 - p;       // 64-row q-group
    const int kt = in_a ? i : i - p - 1;
    const bool diag = (kt == qt);

    if (kt == 0) {  // new q-tile: load Q frags, reset state
      const bf16* Qb = qbuf + (bh * 128 + qt * 4 + w) * 1024;
      qf[0] = *reinterpret_cast<const bf16x8*>(Qb + loff);
      qf[1] = *reinterpret_cast<const bf16x8*>(Qb + 512 + loff);
#pragma unroll
      for (int nd = 0; nd < 4; ++nd) o[nd] = fz;
#pragma unroll
      for (int j = 0; j < 4; ++j) { mrow[j] = -1e30f; lsum[j] = 0.f; }
    }

    // prefetch next tile into the alternate buffer (lands during compute)
    if (i + 1 < 33) {
      const int i2 = i + 1;
      stage((i2 <= p) ? i2 : i2 - p - 1, buf ^ 1);
    }

    // QK^T from LDS (log2-domain scores), elementwise causal mask on diagonal
    f32x4 s4[4];
#pragma unroll
    for (int n = 0; n < 4; ++n) {
      bf16x8 k0 = *reinterpret_cast<const bf16x8*>(&Ks[buf][(n * 2 + 0) * 512 + loff]);
      bf16x8 k1 = *reinterpret_cast<const bf16x8*>(&Ks[buf][(n * 2 + 1) * 512 + loff]);
      s4[n] = mfma16(qf[1], k1, mfma16(qf[0], k0, fz));
    }
    if (diag) {
#pragma unroll
      for (int n = 0; n < 4; ++n)
#pragma unroll
        for (int j = 0; j < 4; ++j)
          if (n * 16 + lr > w * 16 + lg * 4 + j) s4[n][j] = -1e30f;
    }

    // T13 deferred-max: per-lane test; full reduce+rescale only if needed
    float pm[4];
    float dmax = -1e30f;
#pragma unroll
    for (int j = 0; j < 4; ++j) {
      pm[j] = fmaxf(fmaxf(s4[0][j], s4[1][j]), fmaxf(s4[2][j], s4[3][j]));
      dmax = fmaxf(dmax, pm[j] - mrow[j]);
    }
    if (__any(dmax > 11.0f)) {
#pragma unroll
      for (int msk = 1; msk <= 8; msk <<= 1)
#pragma unroll
        for (int j = 0; j < 4; ++j) pm[j] = fmaxf(pm[j], __shfl_xor(pm[j], msk, 64));
#pragma unroll
      for (int j = 0; j < 4; ++j) {
        float mn = fmaxf(mrow[j], pm[j]);
        float alpha = exp2f(mrow[j] - mn);
        mrow[j] = mn;
        lsum[j] *= alpha;
#pragma unroll
        for (int nd = 0; nd < 4; ++nd) o[nd][j] *= alpha;
      }
    }

    // P = exp2(s - m), per-lane partial row-sums (deferred cross-lane reduce)
    float rs[4] = {0.f, 0.f, 0.f, 0.f};
#pragma unroll
    for (int n = 0; n < 4; ++n)
#pragma unroll
      for (int j = 0; j < 4; ++j) {
        float pv = exp2f(s4[n][j] - mrow[j]);
        s4[n][j] = pv;
        rs[j] += pv;
      }
#pragma unroll
    for (int j = 0; j < 4; ++j) lsum[j] += rs[j];

    // P -> per-wave LDS (C-layout -> A-fragment layout)
#pragma unroll
    for (int n = 0; n < 4; ++n)
#pragma unroll
      for (int j = 0; j < 4; ++j)
        Pl[w][lg * 4 + j][n * 16 + lr] = (bf16)s4[n][j];

    // PV from LDS V^T fragments
#pragma unroll
    for (int kk = 0; kk < 2; ++kk) {
      bf16x8 pf = *reinterpret_cast<const bf16x8*>(&Pl[w][lr][kk * 32 + lg * 8]);
#pragma unroll
      for (int nd = 0; nd < 4; ++nd) {
        bf16x8 vfr = *reinterpret_cast<const bf16x8*>(&Vs[buf][(nd * 2 + kk) * 512 + loff]);
        o[nd] = mfma16(pf, vfr, o[nd]);
      }
    }

    if (diag) {  // q-tile finished: reduce lsum, normalize, write out
      float ls[4];
#pragma unroll
      for (int j = 0; j < 4; ++j) ls[j] = lsum[j];
#pragma unroll
      for (int msk = 1; msk <= 8; msk <<= 1)
#pragma unroll
        for (int j = 0; j < 4; ++j) ls[j] += __shfl_xor(ls[j], msk, 64);
      float inv[4];
#pragma unroll
      for (int j = 0; j < 4; ++j) inv[j] = 1.0f / ls[j];
      const int qr0 = (qt * 4 + w) * 16;
#pragma unroll
      for (int nd = 0; nd < 4; ++nd)
#pragma unroll
        for (int j = 0; j < 4; ++j) {
          int srow = qr0 + lg * 4 + j;
          int d = nd * 16 + lr;
          ctx[((long long)(b * SEQ + srow)) * DMODEL + h * HDIM + d] =
              (bf16)(o[nd][j] * inv[j]);
        }
    }

    __syncthreads();  // drains vmcnt (next tile landed) + fences buf reuse
    buf ^= 1;
  }
}

extern "C" void kernel_launch(void* const* d_in, const int* in_sizes, int n_in,
                              void* d_out, int out_size, void* d_ws, size_t ws_size,
                              hipStream_t stream) {
  const float* x      = (const float*)d_in[0];
  const float* w_qkv  = (const float*)d_in[1];
  const float* w_proj = (const float*)d_in[2];
  const float* b_proj = (const float*)d_in[3];
  float* out = (float*)d_out;

  bf16* ws = (bf16*)d_ws;
  bf16* xb     = ws;                   // 4194304 elems
  bf16* wqkvb  = xb + 4194304;         // 3145728
  bf16* wprojb = wqkvb + 3145728;      // 1048576
  bf16* qb     = wprojb + 1048576;     // 4194304 (fragment-ordered, pre-scaled)
  bf16* kb     = qb + 4194304;         // 4194304 (fragment-ordered)
  bf16* vb     = kb + 4194304;         // 4194304 (V^T fragment-ordered)
  bf16* ctxb   = vb + 4194304;         // 4194304   total ~48 MB

  convert_all<<<8192, 256, 0, stream>>>(x, w_qkv, w_proj, xb);
  gemm_bt<0><<<dim3(32, 24), 256, 0, stream>>>(xb, wqkvb, 1024, qb, kb, vb, nullptr, nullptr);
  attn_kernel<<<dim3(16, 32), 256, 0, stream>>>(qb, kb, vb, ctxb);
  gemm_bt<1><<<dim3(32, 8), 256, 0, stream>>>(ctxb, wprojb, 1024, nullptr, nullptr, nullptr,
                                              b_proj, out);
}

// Round 14
// 184.977 us; speedup vs baseline: 1.0975x; 1.0099x over previous
//
#include <hip/hip_runtime.h>

#define SEQ    2048
#define NHEAD  16
#define HDIM   64
#define DMODEL 1024
#define BATCH  2

typedef __bf16 bf16;
typedef __bf16 bf16x8 __attribute__((ext_vector_type(8)));
typedef __bf16 bf16x4v __attribute__((ext_vector_type(4)));
typedef float  f32x4  __attribute__((ext_vector_type(4)));

typedef const __attribute__((address_space(1))) void* gas_ptr;
typedef __attribute__((address_space(3))) void*       las_ptr;

__device__ __forceinline__ f32x4 mfma16(bf16x8 a, bf16x8 b, f32x4 c) {
  return __builtin_amdgcn_mfma_f32_16x16x32_bf16(a, b, c, 0, 0, 0);
}

__device__ __forceinline__ void gload_lds16(const void* g, void* l) {
  __builtin_amdgcn_global_load_lds((gas_ptr)(unsigned long long)g,
                                   (las_ptr)(unsigned long long)l, 16, 0, 0);
}

// ---------------- fp32 -> bf16 conversion (x | w_qkv | w_proj concatenated) ----
__global__ void convert_all(const float* __restrict__ x, const float* __restrict__ wq,
                            const float* __restrict__ wp, bf16* __restrict__ out) {
  const long long NX = 4194304, NQ = 3145728, NP = 1048576;
  long long i = ((long long)blockIdx.x * blockDim.x + threadIdx.x) * 4;
  if (i >= NX + NQ + NP) return;
  const float* src; long long off;
  if (i < NX)           { src = x;  off = i; }
  else if (i < NX + NQ) { src = wq; off = i - NX; }
  else                  { src = wp; off = i - NX - NQ; }
  float4 f = *reinterpret_cast<const float4*>(src + off);
  bf16x4v r;
  r[0] = (bf16)f.x; r[1] = (bf16)f.y; r[2] = (bf16)f.z; r[3] = (bf16)f.w;
  *reinterpret_cast<bf16x4v*>(out + i) = r;
}

// ---------------- GEMM C = A(M,K) * B(N,K)^T, bf16 in, fp32 acc ---------------
// Tile: 128 rows x BN cols. BN=128 (EPI 0) or BN=64 (EPI 1: grid doubles ->
// 2 blocks/CU so barrier stalls overlap). NN = BN/32 n-fragments per wave.
// EPI 0: epilogue scatters Q/K and V^T in LANE-SLOT fragment order (lane l's
//        slice at byte l*16 of each 1KB fragment); Q pre-scaled by SCALE*log2e.
// EPI 1: proj + bias, fp32 out.
template <int EPI, int BN>
__global__ __launch_bounds__(256) void gemm_bt(
    const bf16* __restrict__ A, const bf16* __restrict__ B, int K,
    bf16* __restrict__ q, bf16* __restrict__ k, bf16* __restrict__ v,
    const float* __restrict__ bias, float* __restrict__ out) {
  constexpr int NN = BN / 32;                 // n-frags per wave
  __shared__ alignas(16) bf16 As[2][128 * 32];
  __shared__ alignas(16) bf16 Bs[2][BN * 32];

  const int tid = threadIdx.x;
  const int l = tid & 63, w = tid >> 6;
  const int lr = l & 15, lg = l >> 4;
  const int wr = (w >> 1) * 64, wc = (w & 1) * (BN / 2);
  const long long m0 = (long long)blockIdx.x * 128;
  const long long n0 = (long long)blockIdx.y * BN;
  const int crow = tid >> 2, ccol = (tid & 3) * 8;

  auto stage = [&](int kt, int buf) {
    const bf16* a_src = A + (m0 + crow) * K + (long long)kt * 32 + ccol;
    const bf16* b_src = B + (n0 + crow) * K + (long long)kt * 32 + ccol;
    gload_lds16(a_src,            &As[buf][tid * 8]);
    gload_lds16(a_src + 64LL * K, &As[buf][(tid + 256) * 8]);
    gload_lds16(b_src,            &Bs[buf][tid * 8]);
    if constexpr (BN == 128)
      gload_lds16(b_src + 64LL * K, &Bs[buf][(tid + 256) * 8]);
  };

  f32x4 acc[4][NN];
  const f32x4 fz = {0.f, 0.f, 0.f, 0.f};
#pragma unroll
  for (int m = 0; m < 4; ++m)
#pragma unroll
    for (int n = 0; n < NN; ++n) acc[m][n] = fz;

  stage(0, 0);
  const int nk = K >> 5;
  int cur = 0;
  for (int kt = 0; kt < nk; ++kt) {
    __syncthreads();  // drains vmcnt: buf[cur] staged; prev compute done
    if (kt + 1 < nk) stage(kt + 1, cur ^ 1);
    bf16x8 af[4], bfv[NN];
#pragma unroll
    for (int m = 0; m < 4; ++m)
      af[m] = *reinterpret_cast<const bf16x8*>(&As[cur][(wr + m * 16 + lr) * 32 + lg * 8]);
#pragma unroll
    for (int n = 0; n < NN; ++n)
      bfv[n] = *reinterpret_cast<const bf16x8*>(&Bs[cur][(wc + n * 16 + lr) * 32 + lg * 8]);
#pragma unroll
    for (int m = 0; m < 4; ++m)
#pragma unroll
      for (int n = 0; n < NN; ++n) acc[m][n] = mfma16(af[m], bfv[n], acc[m][n]);
    cur ^= 1;
  }

#pragma unroll
  for (int m = 0; m < 4; ++m) {
#pragma unroll
    for (int n = 0; n < NN; ++n) {
#pragma unroll
      for (int j = 0; j < 4; ++j) {
        long long grow = m0 + wr + m * 16 + lg * 4 + j;   // row in (B*S)
        long long gcol = n0 + wc + n * 16 + lr;           // col in N
        float val = acc[m][n][j];
        if (EPI == 0) {
          int three = (int)(gcol >> 10);
          int rem = (int)(gcol & 1023);
          int h = rem >> 6, d = rem & 63;
          int b = (int)(grow >> 11), s = (int)(grow & 2047);
          int bh = b * NHEAD + h;
          if (three < 2) {
            // Q/K frag [bh][s/16][d/32]; within: (s&15)*8 + ((d>>3)&3)*128 + (d&7)
            int dst = ((bh * 128 + (s >> 4)) * 2 + (d >> 5)) * 512 +
                      (s & 15) * 8 + ((d >> 3) & 3) * 128 + (d & 7);
            // Q pre-scaled by SCALE*log2(e) = 0.125 * 1.4426950 (exp2 softmax)
            if (three == 0) q[dst] = (bf16)(val * 0.18033688f);
            else            k[dst] = (bf16)val;
          } else {
            // V^T frag [bh][d/16][s/64][(s>>5)&1]; within: (d&15)*8 + ((s>>3)&3)*128 + (s&7)
            int dst = (((bh * 4 + (d >> 4)) * 32 + (s >> 6)) * 2 + ((s >> 5) & 1)) * 512 +
                      (d & 15) * 8 + ((s >> 3) & 3) * 128 + (s & 7);
            v[dst] = (bf16)val;
          }
        } else {
          out[grow * 1024 + gcol] = val + bias[gcol];
        }
      }
    }
  }
}

// ---------------- causal flash attention, bf16, hd=64 -------------------------
// Round-14 (attn change): TWO key-tiles per barrier (17 barriers vs 33).
// Pair-granular double buffer: Ks/Vs[2 bufs][2 slots][4096]; prefetch of the
// next PAIR issued before computing the current pair; one __syncthreads per
// pair (vmcnt(0) drain = pipeline wait). Everything else = r13 (passing):
// lane-slot fragments, pairing {p,31-p} flattened to 33 tiles, T13
// deferred-max + exp2-direct + deferred cross-lane sum.
__global__ __launch_bounds__(256, 2) void attn_kernel(
    const bf16* __restrict__ qbuf, const bf16* __restrict__ kbuf,
    const bf16* __restrict__ vbuf, bf16* __restrict__ ctx) {
  const int lid = blockIdx.y * gridDim.x + blockIdx.x;  // [0,512)
  const int xcd = lid & 7;
  const int idx = lid >> 3;                             // [0,64)
  const int bh  = xcd + (idx >> 4) * 8;                 // 4 bh per XCD (K+V L2-fit)
  const int p   = idx & 15;                             // pair index [0,16)
  const int tid = threadIdx.x;
  const int l = tid & 63, w = tid >> 6;                 // 4 waves
  const int lr = l & 15, lg = l >> 4;
  const int loff = l * 8;                               // lane slot (elements)

  __shared__ alignas(16) bf16 Ks[2][2][4096];           // [buf][slot][8KB tile]
  __shared__ alignas(16) bf16 Vs[2][2][4096];
  __shared__ alignas(16) bf16 Pl[4][16][72];            // per-wave P staging

  const bf16* Kg = kbuf + bh * 131072;
  const bf16* Vg = vbuf + bh * 131072;
  const int b = bh >> 4, h = bh & 15;
  const f32x4 fz = {0.f, 0.f, 0.f, 0.f};

  f32x4 o[4];
  float mrow[4], lsum[4];
  bf16x8 qf[2];

  auto tile_kt = [&](int i) { return (i <= p) ? i : i - p - 1; };

  // wave w stages K chunks {2w,2w+1} and V d-block w of tile i into (sb,slot)
  auto stage_tile = [&](int i, int sb, int slot) {
    const int kt = tile_kt(i);
#pragma unroll
    for (int j = 0; j < 2; ++j) {
      const int c = 2 * w + j;
      gload_lds16(Kg + kt * 4096 + c * 512 + loff, &Ks[sb][slot][c * 512 + loff]);
      gload_lds16(Vg + w * 32768 + kt * 1024 + j * 512 + loff, &Vs[sb][slot][c * 512 + loff]);
    }
  };

  // full per-tile body (QK^T -> softmax -> PV [-> writeout on diagonal])
  auto process = [&](int i, int sb, int slot) {
    const bool in_a = (i <= p);
    const int qt = in_a ? p : 31 - p;
    const int kt = in_a ? i : i - p - 1;
    const bool diag = (kt == qt);

    if (kt == 0) {  // new q-tile: load Q frags, reset state
      const bf16* Qb = qbuf + (bh * 128 + qt * 4 + w) * 1024;
      qf[0] = *reinterpret_cast<const bf16x8*>(Qb + loff);
      qf[1] = *reinterpret_cast<const bf16x8*>(Qb + 512 + loff);
#pragma unroll
      for (int nd = 0; nd < 4; ++nd) o[nd] = fz;
#pragma unroll
      for (int j = 0; j < 4; ++j) { mrow[j] = -1e30f; lsum[j] = 0.f; }
    }

    // QK^T from LDS (log2-domain scores), elementwise causal mask on diagonal
    f32x4 s4[4];
#pragma unroll
    for (int n = 0; n < 4; ++n) {
      bf16x8 k0 = *reinterpret_cast<const bf16x8*>(&Ks[sb][slot][(n * 2 + 0) * 512 + loff]);
      bf16x8 k1 = *reinterpret_cast<const bf16x8*>(&Ks[sb][slot][(n * 2 + 1) * 512 + loff]);
      s4[n] = mfma16(qf[1], k1, mfma16(qf[0], k0, fz));
    }
    if (diag) {
#pragma unroll
      for (int n = 0; n < 4; ++n)
#pragma unroll
        for (int j = 0; j < 4; ++j)
          if (n * 16 + lr > w * 16 + lg * 4 + j) s4[n][j] = -1e30f;
    }

    // T13 deferred-max: per-lane test; full reduce+rescale only if needed
    float pm[4];
    float dmax = -1e30f;
#pragma unroll
    for (int j = 0; j < 4; ++j) {
      pm[j] = fmaxf(fmaxf(s4[0][j], s4[1][j]), fmaxf(s4[2][j], s4[3][j]));
      dmax = fmaxf(dmax, pm[j] - mrow[j]);
    }
    if (__any(dmax > 11.0f)) {
#pragma unroll
      for (int msk = 1; msk <= 8; msk <<= 1)
#pragma unroll
        for (int j = 0; j < 4; ++j) pm[j] = fmaxf(pm[j], __shfl_xor(pm[j], msk, 64));
#pragma unroll
      for (int j = 0; j < 4; ++j) {
        float mn = fmaxf(mrow[j], pm[j]);
        float alpha = exp2f(mrow[j] - mn);
        mrow[j] = mn;
        lsum[j] *= alpha;
#pragma unroll
        for (int nd = 0; nd < 4; ++nd) o[nd][j] *= alpha;
      }
    }

    // P = exp2(s - m), per-lane partial row-sums (deferred cross-lane reduce)
    float rs[4] = {0.f, 0.f, 0.f, 0.f};
#pragma unroll
    for (int n = 0; n < 4; ++n)
#pragma unroll
      for (int j = 0; j < 4; ++j) {
        float pv = exp2f(s4[n][j] - mrow[j]);
        s4[n][j] = pv;
        rs[j] += pv;
      }
#pragma unroll
    for (int j = 0; j < 4; ++j) lsum[j] += rs[j];

    // P -> per-wave LDS (C-layout -> A-fragment layout)
#pragma unroll
    for (int n = 0; n < 4; ++n)
#pragma unroll
      for (int j = 0; j < 4; ++j)
        Pl[w][lg * 4 + j][n * 16 + lr] = (bf16)s4[n][j];

    // PV from LDS V^T fragments
#pragma unroll
    for (int kk = 0; kk < 2; ++kk) {
      bf16x8 pf = *reinterpret_cast<const bf16x8*>(&Pl[w][lr][kk * 32 + lg * 8]);
#pragma unroll
      for (int nd = 0; nd < 4; ++nd) {
        bf16x8 vfr = *reinterpret_cast<const bf16x8*>(&Vs[sb][slot][(nd * 2 + kk) * 512 + loff]);
        o[nd] = mfma16(pf, vfr, o[nd]);
      }
    }

    if (diag) {  // q-tile finished: reduce lsum, normalize, write out
      float ls[4];
#pragma unroll
      for (int j = 0; j < 4; ++j) ls[j] = lsum[j];
#pragma unroll
      for (int msk = 1; msk <= 8; msk <<= 1)
#pragma unroll
        for (int j = 0; j < 4; ++j) ls[j] += __shfl_xor(ls[j], msk, 64);
      float inv[4];
#pragma unroll
      for (int j = 0; j < 4; ++j) inv[j] = 1.0f / ls[j];
      const int qr0 = (qt * 4 + w) * 16;
#pragma unroll
      for (int nd = 0; nd < 4; ++nd)
#pragma unroll
        for (int j = 0; j < 4; ++j) {
          int srow = qr0 + lg * 4 + j;
          int d = nd * 16 + lr;
          ctx[((long long)(b * SEQ + srow)) * DMODEL + h * HDIM + d] =
              (bf16)(o[nd][j] * inv[j]);
        }
    }
  };

  stage_tile(0, 0, 0);
  stage_tile(1, 0, 1);
  __syncthreads();   // prologue drain: pair 0 staged
  int buf = 0;

  for (int ip = 0; ip < 17; ++ip) {
    // prefetch next pair into the alternate buffer (lands during compute)
    if (2 * ip + 2 < 33) stage_tile(2 * ip + 2, buf ^ 1, 0);
    if (2 * ip + 3 < 33) stage_tile(2 * ip + 3, buf ^ 1, 1);
    // compute current pair
    process(2 * ip, buf, 0);
    if (2 * ip + 1 < 33) process(2 * ip + 1, buf, 1);
    __syncthreads();  // drains vmcnt (next pair landed) + fences buf reuse
    buf ^= 1;
  }
}

extern "C" void kernel_launch(void* const* d_in, const int* in_sizes, int n_in,
                              void* d_out, int out_size, void* d_ws, size_t ws_size,
                              hipStream_t stream) {
  const float* x      = (const float*)d_in[0];
  const float* w_qkv  = (const float*)d_in[1];
  const float* w_proj = (const float*)d_in[2];
  const float* b_proj = (const float*)d_in[3];
  float* out = (float*)d_out;

  bf16* ws = (bf16*)d_ws;
  bf16* xb     = ws;                   // 4194304 elems
  bf16* wqkvb  = xb + 4194304;         // 3145728
  bf16* wprojb = wqkvb + 3145728;      // 1048576
  bf16* qb     = wprojb + 1048576;     // 4194304 (fragment-ordered, pre-scaled)
  bf16* kb     = qb + 4194304;         // 4194304 (fragment-ordered)
  bf16* vb     = kb + 4194304;         // 4194304 (V^T fragment-ordered)
  bf16* ctxb   = vb + 4194304;         // 4194304   total ~48 MB

  convert_all<<<8192, 256, 0, stream>>>(x, w_qkv, w_proj, xb);
  gemm_bt<0, 128><<<dim3(32, 24), 256, 0, stream>>>(xb, wqkvb, 1024, qb, kb, vb,
                                                    nullptr, nullptr);
  attn_kernel<<<dim3(16, 32), 256, 0, stream>>>(qb, kb, vb, ctxb);
  gemm_bt<1, 64><<<dim3(32, 16), 256, 0, stream>>>(ctxb, wprojb, 1024, nullptr, nullptr,
                                                   nullptr, b_proj, out);
}